// Round 9
// baseline (693.926 us; speedup 1.0000x reference)
//
#include <hip/hip_runtime.h>
#include <hip/hip_bf16.h>
#include <math.h>

typedef __bf16 bf16x8 __attribute__((ext_vector_type(8)));
typedef __bf16 bf16x2 __attribute__((ext_vector_type(2)));
typedef float  f32x4  __attribute__((ext_vector_type(4)));

#define CI_STRIDE 262144   // 64*64*64
#define B_STRIDE  16777216 // 64*CI_STRIDE
#define Z2 68              // z' extent (64 + 2 halo each side)
#define CP 40              // padded ci-half leading dim (32 data + 8 pad; 80 B rows)
#define NROW 12            // 8 data y-rows + 2 halo each side

// ---------------------------------------------------------------------------
// Kernel 1: bf16 weights, layout Wb[t][h][co][ci32]  (h = ci-half).
// Folds 0.1 conv scale, ALPHA factors, cos(pi d)/5^1.5, sh1; center tap t=62
// absorbs the block-diagonal pointwise mix sc (0.25*lin_w).
// ---------------------------------------------------------------------------
__global__ __launch_bounds__(256) void gen_w(const float* __restrict__ tp,
                                             const float* __restrict__ lw0,
                                             const float* __restrict__ lw1,
                                             __bf16* __restrict__ Wb) {
    const int t  = blockIdx.x;            // tap id 0..124, t = dx*25+dy*5+dz
    const int dx = t / 25, dy = (t / 5) % 5, dz = t % 5;
    const float rx = -1.f + 0.5f * (float)dx;
    const float ry = -1.f + 0.5f * (float)dy;
    const float rz = -1.f + 0.5f * (float)dz;
    const float d    = sqrtf(rx * rx + ry * ry + rz * rz);
    const float invd = (d > 0.f) ? (1.f / d) : 0.f;
    const float SQRT3 = 1.7320508075688772f;
    const float sh1_0 = SQRT3 * ry * invd;   // sh1 = sqrt(3)*unit[[1,2,0]]
    const float sh1_1 = SQRT3 * rz * invd;
    const float sh1_2 = SQRT3 * rx * invd;
    float basis[5];
#pragma unroll
    for (int m = 0; m < 5; ++m) {
        float u = (d - 0.25f * (float)m) * 4.0f;
        basis[m] = expf(-u * u) * (1.0f / 1.12f);
    }
    const float S  = cosf(3.14159265358979323846f * d) * (1.0f / 11.180339887498949f);
    const float fA = 0.1f * 0.17677669529663687f * S;
    const float fB = 0.1f * 0.3061862178478972f * 0.5773502691896258f * S;
    const float fC = 0.1f * 0.17677669529663687f * 0.5773502691896258f * S;
    const float fD = fB;

    for (int e = threadIdx.x; e < 4096; e += 256) {
        const int co = e >> 6, ci = e & 63;
        int   tt;
        float f;
        if (ci < 16) {
            if (co < 16) { tt = ci * 16 + co; f = fA; }
            else {
                const int c = co - 16, w = c / 3, kk = c % 3;
                tt = 256 + ci * 16 + w;
                f  = fB * ((kk == 0) ? sh1_0 : (kk == 1) ? sh1_1 : sh1_2);
            }
        } else {
            const int a = ci - 16, uu = a / 3, ii = a % 3;
            const float s1i = (ii == 0) ? sh1_0 : (ii == 1) ? sh1_1 : sh1_2;
            if (co < 16) { tt = 768 + uu * 16 + co; f = fC * s1i; }
            else {
                const int c = co - 16, w = c / 3, kk = c % 3;
                tt = 512 + uu * 16 + w;
                f  = (ii == kk) ? fD : 0.0f;
            }
        }
        float E = 0.f;
#pragma unroll
        for (int m = 0; m < 5; ++m) E += basis[m] * tp[m * 1024 + tt];
        float val = f * E;
        if (t == 62) {  // fold sc into the center tap
            if (ci < 16 && co < 16) {
                val += 0.25f * lw0[ci * 16 + co];
            } else if (ci >= 16 && co >= 16) {
                const int a = co - 16, bq = ci - 16;
                const int wq = a / 3, iq = a % 3, uq = bq / 3, iiq = bq % 3;
                if (iq == iiq) val += 0.25f * lw1[uq * 16 + wq];
            }
        }
        // layout: Wb[((t*2 + h)*64 + co)*32 + ci_lo]
        Wb[((size_t)(t * 2 + (ci >> 5)) * 64 + co) * 32 + (ci & 31)] = (__bf16)val;
    }
}

// ---------------------------------------------------------------------------
// Kernel 2: implicit-GEMM conv, 16x16x32 MFMA. OCCUPANCY restructure.
// Evidence r2-r7: MFMA busy-cycles == the ~255 us pipe floor in EVERY
// variant; only idle moves, and per-wave ILP edits (prefetch, unroll,
// copies) never filled it -- at 232 regs/wave only 2 waves/SIMD were
// resident, so every per-wave stall (staging, L2 A-load, LDS latency,
// barrier jitter) hit a dark matrix pipe.
// Fix: 512-thr blocks, 8 waves; each wave owns 1 y-row x 64 z (N=64) ->
// acc 128->64 AGPR, ~120 unified regs/wave, __launch_bounds__(512,4) pins
// 4 waves/SIMD (2 blocks x 8 waves / CU; LDS 2x65,280 = 130,560 <= 160K).
// Same block tile (64co x 8y x 64z), same LDS plane, same total MFMA work;
// 4 independent-phase waves/SIMD (2 per block x 2 blocks) cover each
// other's latency. Tap body = r7's lean form (no div/mod, imm-offset B
// reads, in-tap A-loads) -- correct once TLP exists to hide its latency.
// ---------------------------------------------------------------------------
__global__ __launch_bounds__(512, 4) void conv_mfma(const float* __restrict__ x,
                                                    const __bf16* __restrict__ Wb,
                                                    float* __restrict__ out) {
    __shared__ __align__(16) __bf16 xs[NROW * Z2 * CP];   // 65,280 B
    const int tid = threadIdx.x;
    const int l = tid & 63, w = tid >> 6;     // 8 waves
    const int q = l >> 4, i16 = l & 15;
    const int b  = blockIdx.x >> 9;
    const int xc = (blockIdx.x >> 3) & 63;
    const int y0 = (blockIdx.x & 7) << 3;

    f32x4 acc[4][4];                          // M=64 (4 mt), N=64 (4 nt)
#pragma unroll
    for (int mt = 0; mt < 4; ++mt)
#pragma unroll
        for (int nt = 0; nt < 4; ++nt) acc[mt][nt] = (f32x4)(0.f);

    // zero the z-halo columns z' in {0,1,66,67}, ci 0..31 (staging never
    // writes them; values persist across all planes)
    if (tid < NROW * 4 * 4) {
        const int r = tid >> 4, rem = tid & 15;
        const int zs = rem >> 2, c8 = (rem & 3) << 3;
        const int zp = (zs < 2) ? zs : (64 + zs);
        bf16x8 zz = {(__bf16)0.f, (__bf16)0.f, (__bf16)0.f, (__bf16)0.f,
                     (__bf16)0.f, (__bf16)0.f, (__bf16)0.f, (__bf16)0.f};
        *(bf16x8*)(xs + ((size_t)r * Z2 + zp) * CP + c8) = zz;
    }

    const float* xb = x + (size_t)b * B_STRIDE;

    // per-lane bases (loop-invariant). Wave w's output row = y0 + w;
    // its tap-dy=0 LDS row = w.
    const __bf16* const bds = xs + ((size_t)w * Z2 + i16) * CP + q * 8;
    const int lane_a = i16 * 32 + q * 8;

    for (int h = 0; h < 2; ++h) {
        for (int dx = 0; dx < 5; ++dx) {
            __syncthreads();   // all waves done reading the previous plane
            {   // stage plane x' = xc+dx-2, rows y' = y0-2 .. y0+9, ci-half h
                // 12 rows over 8 waves: wave w -> row w (+ row w+8 if w<4)
                const int xp = xc + dx - 2;
                const bool xok = (xp >= 0) && (xp < 64);
                for (int r = w; r < NROW; r += 8) {
                    const int yp = y0 + r - 2;
                    const bool ok = xok && (yp >= 0) && (yp < 64);
                    const float* src = xb + (size_t)(h * 32) * CI_STRIDE
                                     + (size_t)xp * 4096 + yp * 64 + l;
                    __bf16* dst = xs + ((size_t)r * Z2 + 2 + l) * CP;
                    if (ok) {
#pragma unroll
                        for (int ci = 0; ci < 32; ci += 2) {
                            const float a0 = src[(size_t)ci * CI_STRIDE];
                            const float a1 = src[(size_t)(ci + 1) * CI_STRIDE];
                            bf16x2 pk = {(__bf16)a0, (__bf16)a1};
                            *(bf16x2*)(dst + ci) = pk;
                        }
                    } else {
                        bf16x2 zz = {(__bf16)0.f, (__bf16)0.f};
#pragma unroll
                        for (int ci = 0; ci < 32; ci += 2) *(bf16x2*)(dst + ci) = zz;
                    }
                }
            }
            __syncthreads();

            // 25 taps: dy runtime (pressure-bounded), dz unrolled (no div/mod).
            // B: imm offsets off brow (walked += Z2*CP per dy).
            // A: offsets off wrow (walked += 5*4096 per dy).
            const __bf16* wrow = Wb + (size_t)(dx * 50 + h) * 2048 + lane_a;
            const __bf16* brow = bds;
#pragma unroll 1
            for (int dy = 0; dy < 5; ++dy) {
#pragma unroll
                for (int dz = 0; dz < 5; ++dz) {
                    bf16x8 Af[4], Bf[4];
#pragma unroll
                    for (int mt = 0; mt < 4; ++mt)
                        Af[mt] = *(const bf16x8*)(wrow + dz * 4096 + mt * 512);
#pragma unroll
                    for (int zt = 0; zt < 4; ++zt)
                        Bf[zt] = *(const bf16x8*)(brow + (dz + zt * 16) * CP);
                    __builtin_amdgcn_s_setprio(1);
#pragma unroll
                    for (int mt = 0; mt < 4; ++mt)
#pragma unroll
                        for (int nt = 0; nt < 4; ++nt)
                            acc[mt][nt] = __builtin_amdgcn_mfma_f32_16x16x32_bf16(
                                Af[mt], Bf[nt], acc[mt][nt], 0, 0, 0);
                    __builtin_amdgcn_s_setprio(0);
                }
                wrow += 5 * 4096;
                brow += Z2 * CP;
            }
        }
    }

    // epilogue: D layout col(n)=lane&15, row(m)=q*4+j; wave w -> y = y0+w
    const size_t ob = (size_t)b * B_STRIDE + (size_t)xc * 4096;
    const int y = y0 + w;
#pragma unroll
    for (int mt = 0; mt < 4; ++mt)
#pragma unroll
        for (int j = 0; j < 4; ++j) {
            const int co = mt * 16 + q * 4 + j;
            float* op = out + ob + (size_t)co * CI_STRIDE + y * 64;
#pragma unroll
            for (int nt = 0; nt < 4; ++nt) {
                const int z = nt * 16 + i16;
                op[z] = acc[mt][nt][j];
            }
        }
}

extern "C" void kernel_launch(void* const* d_in, const int* in_sizes, int n_in,
                              void* d_out, int out_size, void* d_ws, size_t ws_size,
                              hipStream_t stream) {
    (void)in_sizes; (void)n_in; (void)out_size; (void)ws_size;
    const float* x   = (const float*)d_in[0];  // (2, 64, 64, 64, 64) fp32
    const float* lw0 = (const float*)d_in[1];  // (16, 16)
    const float* lw1 = (const float*)d_in[2];  // (16, 16)
    const float* tp  = (const float*)d_in[3];  // (5, 1024)
    float* out = (float*)d_out;
    __bf16* Wb = (__bf16*)d_ws;                // 125*2*64*32*2 B = 1.0 MB

    gen_w<<<125, 256, 0, stream>>>(tp, lw0, lw1, Wb);
    conv_mfma<<<1024, 512, 0, stream>>>(x, Wb, out);
}